// Round 1
// baseline (608.377 us; speedup 1.0000x reference)
//
#include <hip/hip_runtime.h>
#include <hip/hip_bf16.h>
#include <stdint.h>

#define DIM 512

typedef short short8 __attribute__((ext_vector_type(8)));
typedef float floatx4 __attribute__((ext_vector_type(4)));

// f32 -> bf16 round-to-nearest-even
__device__ inline unsigned short f2b(float x){
  uint32_t u = __float_as_uint(x);
  u += 0x7FFFu + ((u >> 16) & 1u);
  return (unsigned short)(u >> 16);
}
__device__ inline float blo(uint32_t u){ return __uint_as_float(u << 16); }
__device__ inline float bhi(uint32_t u){ return __uint_as_float(u & 0xFFFF0000u); }

// ---------------- CSR build ----------------
__global__ void k_init(int* __restrict__ cnt, int* __restrict__ fill, int n){
  int i = blockIdx.x * blockDim.x + threadIdx.x;
  if (i < n){ cnt[i] = 0; fill[i] = 0; }
}

__global__ void k_count(const int* __restrict__ ei, int* __restrict__ cnt, int E){
  int e = blockIdx.x * blockDim.x + threadIdx.x;
  if (e < E) atomicAdd(&cnt[ei[E + e]], 1);
}

__global__ void k_dis(const int* __restrict__ cnt, float* __restrict__ dis, int n){
  int i = blockIdx.x * blockDim.x + threadIdx.x;
  if (i < n) dis[i] = rsqrtf((float)cnt[i] + 1.0f);   // +1 self-loop; deg>=1 always
}

__global__ __launch_bounds__(1024)
void k_scan(const int* __restrict__ cnt, int* __restrict__ rowptr, int n){
  __shared__ int sh[1024];
  __shared__ int carry;
  const int tid = threadIdx.x;
  if (tid == 0) carry = 0;
  __syncthreads();
  for (int base = 0; base < n; base += 1024){
    int i = base + tid;
    int v = (i < n) ? cnt[i] : 0;
    sh[tid] = v;
    __syncthreads();
    for (int off = 1; off < 1024; off <<= 1){
      int t = (tid >= off) ? sh[tid - off] : 0;
      __syncthreads();
      sh[tid] += t;
      __syncthreads();
    }
    int c = carry;
    if (i < n) rowptr[i] = c + sh[tid] - v;   // exclusive prefix
    __syncthreads();
    if (tid == 0) carry = c + sh[1023];
    __syncthreads();
  }
  if (tid == 0) rowptr[n] = carry;
}

__global__ void k_fill(const int* __restrict__ ei, const int* __restrict__ rowptr,
                       int* __restrict__ fill, int* __restrict__ colidx, int E){
  int e = blockIdx.x * blockDim.x + threadIdx.x;
  if (e < E){
    int d = ei[E + e];
    int pos = rowptr[d] + atomicAdd(&fill[d], 1);
    colidx[pos] = ei[e];
  }
}

// ---------------- dtype prep ----------------
__global__ void k_cvt(const float* __restrict__ x, unsigned short* __restrict__ xb, long n4){
  long i = blockIdx.x * (long)blockDim.x + threadIdx.x;
  if (i < n4){
    float4 v = ((const float4*)x)[i];
    ushort4 o;
    o.x = f2b(v.x); o.y = f2b(v.y); o.z = f2b(v.z); o.w = f2b(v.w);
    ((ushort4*)xb)[i] = o;
  }
}

// Pack W [k][n] row-major f32 -> bf16 layout [n>>4][k>>3][n&15][k&7]
// so a B-fragment load (lane: 8 consecutive k for fixed n) is one 16B load.
__global__ void k_pack(const float* __restrict__ W, unsigned short* __restrict__ Wp){
  int g = blockIdx.x * blockDim.x + threadIdx.x;   // 0..DIM*DIM-1
  int k = g >> 9, n = g & 511;
  int idx = ((n >> 4) << 13) + ((k >> 3) << 7) + ((n & 15) << 3) + (k & 7);
  Wp[idx] = f2b(W[g]);
}

// ---------------- GEMM: C = dis-scaled (A @ W), bf16 in, bf16 out ----------------
// Block: 256 thr = 4 waves. Tile 64(M) x 64(N). Wave w: rows m0..m0+15, all 64 cols.
// A frag: lane l holds A[m0+(l&15)][ks*32 + (l>>4)*8 + j]  (16B contiguous load)
// B frag: from packed layout (16B contiguous load)
// D map: row = (l>>4)*4 + r, col = l&15   [m89-verified]
__global__ __launch_bounds__(256)
void k_gemm(const unsigned short* __restrict__ A, const unsigned short* __restrict__ Wp,
            const float* __restrict__ dis, unsigned short* __restrict__ C, int Nr)
{
  const int wave = threadIdx.x >> 6;
  const int lane = threadIdx.x & 63;
  const int m0 = blockIdx.x * 64 + wave * 16;
  if (m0 >= Nr) return;               // no barriers in kernel -> safe
  const int l15 = lane & 15;
  const int q   = lane >> 4;
  int arow = m0 + l15; if (arow >= Nr) arow = Nr - 1;
  const unsigned short* ap = A + (size_t)arow * DIM + q * 8;
  const unsigned short* bp = Wp + (size_t)(blockIdx.y * 4) * 8192 + q * 128 + l15 * 8;
  floatx4 acc0 = {0,0,0,0}, acc1 = {0,0,0,0}, acc2 = {0,0,0,0}, acc3 = {0,0,0,0};
  #pragma unroll
  for (int ks = 0; ks < 16; ++ks){
    short8 a  = *(const short8*)(ap + ks * 32);
    short8 b0 = *(const short8*)(bp + ks * 512);
    short8 b1 = *(const short8*)(bp + 8192  + ks * 512);
    short8 b2 = *(const short8*)(bp + 16384 + ks * 512);
    short8 b3 = *(const short8*)(bp + 24576 + ks * 512);
    acc0 = __builtin_amdgcn_mfma_f32_16x16x32_bf16(a, b0, acc0, 0, 0, 0);
    acc1 = __builtin_amdgcn_mfma_f32_16x16x32_bf16(a, b1, acc1, 0, 0, 0);
    acc2 = __builtin_amdgcn_mfma_f32_16x16x32_bf16(a, b2, acc2, 0, 0, 0);
    acc3 = __builtin_amdgcn_mfma_f32_16x16x32_bf16(a, b3, acc3, 0, 0, 0);
  }
  const int n0 = blockIdx.y * 64 + l15;
  #pragma unroll
  for (int r = 0; r < 4; ++r){
    int row = m0 + q * 4 + r;
    if (row < Nr){
      float ds = dis[row];
      size_t base = (size_t)row * DIM + n0;
      C[base     ] = f2b(acc0[r] * ds);
      C[base + 16] = f2b(acc1[r] * ds);
      C[base + 32] = f2b(acc2[r] * ds);
      C[base + 48] = f2b(acc3[r] * ds);
    }
  }
}

// ---------------- Aggregation: out_i = dis_i * (H[i] + sum_{s in N(i)} H[s]) + b ----
template<int RELU, int OUTBF16>
__global__ __launch_bounds__(256)
void k_agg(const unsigned short* __restrict__ H, const int* __restrict__ rowptr,
           const int* __restrict__ colidx, const float* __restrict__ dis,
           const float* __restrict__ bias, void* __restrict__ outp)
{
  const int i = blockIdx.x;
  const int f = threadIdx.x * 2;
  const float di = dis[i];
  uint32_t u = *(const uint32_t*)(H + (size_t)i * DIM + f);
  float a0 = blo(u), a1 = bhi(u);
  const int r1 = rowptr[i + 1];
  for (int e = rowptr[i]; e < r1; ++e){
    int s = colidx[e];
    uint32_t v = *(const uint32_t*)(H + (size_t)s * DIM + f);
    a0 += blo(v); a1 += bhi(v);
  }
  a0 = a0 * di + bias[f];
  a1 = a1 * di + bias[f + 1];
  if (RELU){ a0 = fmaxf(a0, 0.0f); a1 = fmaxf(a1, 0.0f); }
  if (OUTBF16){
    uint32_t o = (uint32_t)f2b(a0) | ((uint32_t)f2b(a1) << 16);
    ((uint32_t*)outp)[(size_t)i * (DIM / 2) + threadIdx.x] = o;
  } else {
    float2 o; o.x = a0; o.y = a1;
    ((float2*)outp)[(size_t)i * (DIM / 2) + threadIdx.x] = o;
  }
}

// ---------------- launch ----------------
extern "C" void kernel_launch(void* const* d_in, const int* in_sizes, int n_in,
                              void* d_out, int out_size, void* d_ws, size_t ws_size,
                              hipStream_t stream)
{
  const float* x  = (const float*)d_in[0];
  const int*   ei = (const int*)d_in[1];
  const float* W1 = (const float*)d_in[2];
  const float* b1 = (const float*)d_in[3];
  const float* W2 = (const float*)d_in[4];
  const float* b2 = (const float*)d_in[5];
  const int N = in_sizes[0] / DIM;
  const int E = in_sizes[1] / 2;

  char* p = (char*)d_ws;
  auto alloc = [&](size_t bytes) -> char* {
    char* r = p; p += (bytes + 255) & ~(size_t)255; return r;
  };
  unsigned short* xb   = (unsigned short*)alloc((size_t)N * DIM * 2);
  unsigned short* hb   = (unsigned short*)alloc((size_t)N * DIM * 2);
  unsigned short* W1p  = (unsigned short*)alloc((size_t)DIM * DIM * 2);
  unsigned short* W2p  = (unsigned short*)alloc((size_t)DIM * DIM * 2);
  float* dis   = (float*)alloc((size_t)N * 4);
  int*   cnt   = (int*)alloc((size_t)N * 4);
  int*   fill  = (int*)alloc((size_t)N * 4);
  int*   rowptr= (int*)alloc((size_t)(N + 1) * 4);
  int*   colidx= (int*)alloc((size_t)E * 4);

  // CSR + normalization
  k_init<<<(N + 255) / 256, 256, 0, stream>>>(cnt, fill, N);
  k_count<<<(E + 255) / 256, 256, 0, stream>>>(ei, cnt, E);
  k_dis<<<(N + 255) / 256, 256, 0, stream>>>(cnt, dis, N);
  k_scan<<<1, 1024, 0, stream>>>(cnt, rowptr, N);
  k_fill<<<(E + 255) / 256, 256, 0, stream>>>(ei, rowptr, fill, colidx, E);

  // dtype prep
  long n4 = (long)N * DIM / 4;
  k_cvt<<<(int)((n4 + 255) / 256), 256, 0, stream>>>(x, xb, n4);
  k_pack<<<(DIM * DIM) / 256, 256, 0, stream>>>(W1, W1p);
  k_pack<<<(DIM * DIM) / 256, 256, 0, stream>>>(W2, W2p);

  dim3 gg((N + 63) / 64, DIM / 64);
  // layer 1: H1 = dis * (x @ W1); x2 = relu(dis * agg(H1) + b1) in bf16 (into xb)
  k_gemm<<<gg, 256, 0, stream>>>(xb, W1p, dis, hb, N);
  k_agg<1, 1><<<N, 256, 0, stream>>>(hb, rowptr, colidx, dis, b1, xb);
  // layer 2: H2 = dis * (x2 @ W2); out = dis * agg(H2) + b2 in f32
  k_gemm<<<gg, 256, 0, stream>>>(xb, W2p, dis, hb, N);
  k_agg<0, 0><<<N, 256, 0, stream>>>(hb, rowptr, colidx, dis, b2, d_out);
}

// Round 2
// 445.725 us; speedup vs baseline: 1.3649x; 1.3649x over previous
//
#include <hip/hip_runtime.h>
#include <hip/hip_bf16.h>
#include <stdint.h>

#define DIM 512

typedef short short8 __attribute__((ext_vector_type(8)));
typedef float floatx4 __attribute__((ext_vector_type(4)));

// f32 -> bf16 round-to-nearest-even
__device__ inline unsigned short f2b(float x){
  uint32_t u = __float_as_uint(x);
  u += 0x7FFFu + ((u >> 16) & 1u);
  return (unsigned short)(u >> 16);
}
__device__ inline float blo(uint32_t u){ return __uint_as_float(u << 16); }
__device__ inline float bhi(uint32_t u){ return __uint_as_float(u & 0xFFFF0000u); }

// ---------------- CSR build ----------------
__global__ void k_init(int* __restrict__ cnt, int* __restrict__ fill, int n){
  int i = blockIdx.x * blockDim.x + threadIdx.x;
  if (i < n){ cnt[i] = 0; fill[i] = 0; }
}

__global__ void k_count(const int* __restrict__ ei, int* __restrict__ cnt, int E){
  int e = blockIdx.x * blockDim.x + threadIdx.x;
  if (e < E) atomicAdd(&cnt[ei[E + e]], 1);
}

__global__ void k_dis(const int* __restrict__ cnt, float* __restrict__ dis, int n){
  int i = blockIdx.x * blockDim.x + threadIdx.x;
  if (i < n) dis[i] = rsqrtf((float)cnt[i] + 1.0f);   // +1 self-loop; deg>=1 always
}

// ---- hierarchical exclusive scan of cnt[0..n) -> rowptr[0..n], 1024 elems/block ----
__global__ __launch_bounds__(256)
void k_bsum(const int* __restrict__ cnt, int* __restrict__ partial, int n){
  __shared__ int sh[4];
  int t = threadIdx.x;
  int base = blockIdx.x * 1024 + t * 4;
  int s = 0;
  if (base + 3 < n){
    int4 v = *(const int4*)(cnt + base);
    s = v.x + v.y + v.z + v.w;
  } else {
    for (int j = 0; j < 4; ++j) if (base + j < n) s += cnt[base + j];
  }
  for (int d = 32; d; d >>= 1) s += __shfl_down(s, d);
  if ((t & 63) == 0) sh[t >> 6] = s;
  __syncthreads();
  if (t == 0) partial[blockIdx.x] = sh[0] + sh[1] + sh[2] + sh[3];
}

__global__ void k_pscan(int* __restrict__ partial, int* __restrict__ rowptr, int nb, int n){
  int t = threadIdx.x;  // 64 threads, nb <= 64
  int v = (t < nb) ? partial[t] : 0;
  int incl = v;
  #pragma unroll
  for (int d = 1; d < 64; d <<= 1){
    int u = __shfl_up(incl, d);
    if (t >= d) incl += u;
  }
  if (t < nb) partial[t] = incl - v;   // exclusive
  if (t == 63) rowptr[n] = incl;       // grand total
}

__global__ __launch_bounds__(256)
void k_fscan(const int* __restrict__ cnt, const int* __restrict__ partial,
             int* __restrict__ rowptr, int n){
  __shared__ int sh[256];
  int t = threadIdx.x;
  int base = blockIdx.x * 1024 + t * 4;
  int v0=0, v1=0, v2=0, v3=0;
  if (base + 3 < n){
    int4 v = *(const int4*)(cnt + base);
    v0=v.x; v1=v.y; v2=v.z; v3=v.w;
  } else {
    if (base   < n) v0 = cnt[base];
    if (base+1 < n) v1 = cnt[base+1];
    if (base+2 < n) v2 = cnt[base+2];
    if (base+3 < n) v3 = cnt[base+3];
  }
  int tsum = v0 + v1 + v2 + v3;
  sh[t] = tsum;
  __syncthreads();
  for (int off = 1; off < 256; off <<= 1){
    int u = (t >= off) ? sh[t - off] : 0;
    __syncthreads();
    sh[t] += u;
    __syncthreads();
  }
  int excl = sh[t] - tsum + partial[blockIdx.x];
  if (base   < n) rowptr[base  ] = excl;
  if (base+1 < n) rowptr[base+1] = excl + v0;
  if (base+2 < n) rowptr[base+2] = excl + v0 + v1;
  if (base+3 < n) rowptr[base+3] = excl + v0 + v1 + v2;
}

__global__ void k_fill(const int* __restrict__ ei, const int* __restrict__ rowptr,
                       int* __restrict__ fill, int* __restrict__ colidx, int E){
  int e = blockIdx.x * blockDim.x + threadIdx.x;
  if (e < E){
    int d = ei[E + e];
    int pos = rowptr[d] + atomicAdd(&fill[d], 1);
    colidx[pos] = ei[e];
  }
}

// ---------------- dtype prep ----------------
__global__ void k_cvt(const float* __restrict__ x, unsigned short* __restrict__ xb, long n4){
  long i = blockIdx.x * (long)blockDim.x + threadIdx.x;
  if (i < n4){
    float4 v = ((const float4*)x)[i];
    ushort4 o;
    o.x = f2b(v.x); o.y = f2b(v.y); o.z = f2b(v.z); o.w = f2b(v.w);
    ((ushort4*)xb)[i] = o;
  }
}

// Pack W [k][n] row-major f32 -> bf16 layout [n>>4][k>>3][n&15][k&7]
__global__ void k_pack(const float* __restrict__ W, unsigned short* __restrict__ Wp){
  int g = blockIdx.x * blockDim.x + threadIdx.x;   // 0..DIM*DIM-1
  int k = g >> 9, n = g & 511;
  int idx = ((n >> 4) << 13) + ((k >> 3) << 7) + ((n & 15) << 3) + (k & 7);
  Wp[idx] = f2b(W[g]);
}

// ---------------- GEMM: C = dis-scaled (A @ W), bf16 in, bf16 out ----------------
// Block 256 thr = 4 waves. Block tile: 256(M) x 128(N). Wave: 64(M) x 128(N).
// acc = 4 m-subs x 8 n-tiles x floatx4 = 128 VGPR.
// Reuse: each B frag feeds 4 MFMAs, each A frag feeds 8 MFMAs.
// D map: row = q*4 + r, col = l15   [m89-verified]
__global__ __launch_bounds__(256, 2)
void k_gemm(const unsigned short* __restrict__ A, const unsigned short* __restrict__ Wp,
            const float* __restrict__ dis, unsigned short* __restrict__ C, int Nr)
{
  const int wave = threadIdx.x >> 6;
  const int lane = threadIdx.x & 63;
  const int l15  = lane & 15;
  const int q    = lane >> 4;
  const int R0   = blockIdx.x * 256 + wave * 64;   // wave's first row
  if (R0 >= Nr) return;                             // no barriers -> safe
  const int nb   = blockIdx.y * 128;                // col base

  const unsigned short* ap[4];
  #pragma unroll
  for (int s = 0; s < 4; ++s){
    int ar = R0 + s * 16 + l15;
    if (ar >= Nr) ar = Nr - 1;
    ap[s] = A + (size_t)ar * DIM + q * 8;
  }
  const unsigned short* bp = Wp + (size_t)(blockIdx.y * 8) * 8192 + q * 128 + l15 * 8;

  floatx4 acc[4][8];
  #pragma unroll
  for (int s = 0; s < 4; ++s)
    #pragma unroll
    for (int nt = 0; nt < 8; ++nt)
      acc[s][nt] = (floatx4){0,0,0,0};

  #pragma unroll 4
  for (int ks = 0; ks < 16; ++ks){
    short8 a0 = *(const short8*)(ap[0] + ks * 32);
    short8 a1 = *(const short8*)(ap[1] + ks * 32);
    short8 a2 = *(const short8*)(ap[2] + ks * 32);
    short8 a3 = *(const short8*)(ap[3] + ks * 32);
    #pragma unroll
    for (int nt = 0; nt < 8; ++nt){
      short8 b = *(const short8*)(bp + nt * 8192 + ks * 512);
      acc[0][nt] = __builtin_amdgcn_mfma_f32_16x16x32_bf16(a0, b, acc[0][nt], 0, 0, 0);
      acc[1][nt] = __builtin_amdgcn_mfma_f32_16x16x32_bf16(a1, b, acc[1][nt], 0, 0, 0);
      acc[2][nt] = __builtin_amdgcn_mfma_f32_16x16x32_bf16(a2, b, acc[2][nt], 0, 0, 0);
      acc[3][nt] = __builtin_amdgcn_mfma_f32_16x16x32_bf16(a3, b, acc[3][nt], 0, 0, 0);
    }
  }

  #pragma unroll
  for (int s = 0; s < 4; ++s){
    #pragma unroll
    for (int r = 0; r < 4; ++r){
      int row = R0 + s * 16 + q * 4 + r;
      if (row < Nr){
        float ds = dis[row];
        size_t base = (size_t)row * DIM + nb + l15;
        #pragma unroll
        for (int nt = 0; nt < 8; ++nt)
          C[base + nt * 16] = f2b(acc[s][nt][r] * ds);
      }
    }
  }
}

// ---------------- Aggregation: out_i = dis_i * (H[i] + sum_{s in N(i)} H[s]) + b ----
// 2 nodes per block; 128 threads/node; 4 bf16 per thread (uint2 loads).
template<int RELU, int OUTBF16>
__global__ __launch_bounds__(256)
void k_agg(const unsigned short* __restrict__ H, const int* __restrict__ rowptr,
           const int* __restrict__ colidx, const float* __restrict__ dis,
           const float* __restrict__ bias, void* __restrict__ outp, int Nn)
{
  const int i = blockIdx.x * 2 + (threadIdx.x >> 7);
  if (i >= Nn) return;
  const int j = threadIdx.x & 127;
  const int f = j * 4;
  const float di = dis[i];
  uint2 u = *(const uint2*)(H + (size_t)i * DIM + f);
  float a0 = blo(u.x), a1 = bhi(u.x), a2 = blo(u.y), a3 = bhi(u.y);
  const int r1 = rowptr[i + 1];
  for (int e = rowptr[i]; e < r1; ++e){
    int s = colidx[e];
    uint2 v = *(const uint2*)(H + (size_t)s * DIM + f);
    a0 += blo(v.x); a1 += bhi(v.x); a2 += blo(v.y); a3 += bhi(v.y);
  }
  a0 = a0 * di + bias[f];
  a1 = a1 * di + bias[f + 1];
  a2 = a2 * di + bias[f + 2];
  a3 = a3 * di + bias[f + 3];
  if (RELU){
    a0 = fmaxf(a0, 0.0f); a1 = fmaxf(a1, 0.0f);
    a2 = fmaxf(a2, 0.0f); a3 = fmaxf(a3, 0.0f);
  }
  if (OUTBF16){
    uint2 o;
    o.x = (uint32_t)f2b(a0) | ((uint32_t)f2b(a1) << 16);
    o.y = (uint32_t)f2b(a2) | ((uint32_t)f2b(a3) << 16);
    ((uint2*)outp)[(size_t)i * 128 + j] = o;
  } else {
    float4 o; o.x = a0; o.y = a1; o.z = a2; o.w = a3;
    ((float4*)outp)[(size_t)i * 128 + j] = o;
  }
}

// ---------------- launch ----------------
extern "C" void kernel_launch(void* const* d_in, const int* in_sizes, int n_in,
                              void* d_out, int out_size, void* d_ws, size_t ws_size,
                              hipStream_t stream)
{
  const float* x  = (const float*)d_in[0];
  const int*   ei = (const int*)d_in[1];
  const float* W1 = (const float*)d_in[2];
  const float* b1 = (const float*)d_in[3];
  const float* W2 = (const float*)d_in[4];
  const float* b2 = (const float*)d_in[5];
  const int N = in_sizes[0] / DIM;
  const int E = in_sizes[1] / 2;

  char* p = (char*)d_ws;
  auto alloc = [&](size_t bytes) -> char* {
    char* r = p; p += (bytes + 255) & ~(size_t)255; return r;
  };
  unsigned short* xb   = (unsigned short*)alloc((size_t)N * DIM * 2);
  unsigned short* hb   = (unsigned short*)alloc((size_t)N * DIM * 2);
  unsigned short* W1p  = (unsigned short*)alloc((size_t)DIM * DIM * 2);
  unsigned short* W2p  = (unsigned short*)alloc((size_t)DIM * DIM * 2);
  float* dis    = (float*)alloc((size_t)N * 4);
  int*   cnt    = (int*)alloc((size_t)N * 4);
  int*   fill   = (int*)alloc((size_t)N * 4);
  int*   rowptr = (int*)alloc((size_t)(N + 1) * 4);
  int*   colidx = (int*)alloc((size_t)E * 4);
  int*   partial= (int*)alloc(64 * 4);

  const int nsb = (N + 1023) / 1024;   // scan blocks (<=64)

  // CSR + normalization
  k_init<<<(N + 255) / 256, 256, 0, stream>>>(cnt, fill, N);
  k_count<<<(E + 255) / 256, 256, 0, stream>>>(ei, cnt, E);
  k_dis<<<(N + 255) / 256, 256, 0, stream>>>(cnt, dis, N);
  k_bsum<<<nsb, 256, 0, stream>>>(cnt, partial, N);
  k_pscan<<<1, 64, 0, stream>>>(partial, rowptr, nsb, N);
  k_fscan<<<nsb, 256, 0, stream>>>(cnt, partial, rowptr, N);
  k_fill<<<(E + 255) / 256, 256, 0, stream>>>(ei, rowptr, fill, colidx, E);

  // dtype prep
  long n4 = (long)N * DIM / 4;
  k_cvt<<<(int)((n4 + 255) / 256), 256, 0, stream>>>(x, xb, n4);
  k_pack<<<(DIM * DIM) / 256, 256, 0, stream>>>(W1, W1p);
  k_pack<<<(DIM * DIM) / 256, 256, 0, stream>>>(W2, W2p);

  dim3 gg((N + 255) / 256, DIM / 128);
  // layer 1: H1 = dis * (x @ W1); x2 = relu(dis * agg(H1) + b1) in bf16 (into xb)
  k_gemm<<<gg, 256, 0, stream>>>(xb, W1p, dis, hb, N);
  k_agg<1, 1><<<(N + 1) / 2, 256, 0, stream>>>(hb, rowptr, colidx, dis, b1, xb, N);
  // layer 2: H2 = dis * (x2 @ W2); out = dis * agg(H2) + b2 in f32
  k_gemm<<<gg, 256, 0, stream>>>(xb, W2p, dis, hb, N);
  k_agg<0, 0><<<(N + 1) / 2, 256, 0, stream>>>(hb, rowptr, colidx, dis, b2, d_out, N);
}